// Round 4
// baseline (472.105 us; speedup 1.0000x reference)
//
#include <hip/hip_runtime.h>

// MCH remap via cell-indexed Bloom signatures + aux-window exact resolution.
//
// Round-7: two levers on the 33.5M random 8B filter gathers.
// (1) PHASE-SHARDED FILTER RESIDENCY: r3 showed ~480 MB of filter L2-miss
//     traffic (FETCH 649 vs 134 streams; 4 MB filter == 4 MB per-XCD L2,
//     churns vs streams). Split filter by cell bit 18 (= value bit 30)
//     into two 2 MB halves; pass 0 handles shard-0 lanes and stores FULL
//     int4 results (zch placeholder elsewhere, coalesced write-once);
//     pass 1 handles shard-1 lanes and stores ONLY true hits (~33K scalar
//     stores; placeholders already correct for misses/fp). Inactive lanes
//     gather a wave-uniform dummy cell INSIDE the hot shard (1 coalesced
//     request, no cold-shard pollution). Cost: values re-streamed once.
// (2) FORCED 16-DEEP MLP: r3's VGPR=36 proves the compiler batched the 16
//     gathers ~2-4 deep. sched_barrier(0) between issue-all and use-all
//     forces all 16 results live -> real outstanding requests.
//
// Resolution invariants (any sorted table, any cell shift SH):
//   idx <  aux[k]   => table[idx] <  (k<<SH)    <= v  (counted, all < v)
//   idx >= aux[k+1] => table[idx] >= (k+1)<<SH  >  v  (never counted/eq)
// and if table[m] == v the clamped-to-z window includes index m.

typedef int vint4 __attribute__((ext_vector_type(4)));
typedef unsigned long long u64;

#define HK 2654435761u                      // Knuth multiplicative hash

__device__ __forceinline__ u64 sig_mask(unsigned v) {
    unsigned h = v * HK;                    // bits 8..31 used, disjoint 6-bit fields
    return (1ULL << (h >> 26)) | (1ULL << ((h >> 20) & 63)) |
           (1ULL << ((h >> 14) & 63)) | (1ULL << ((h >> 8) & 63));
}

// ---- build 1: aux[k] = lower_bound(table[:m], k<<SH), O(z) scatter ----
template <int BITS>
__global__ __launch_bounds__(256) void build_aux_scatter(
    const int* __restrict__ table, int m, int* __restrict__ aux) {
    const int SH = 31 - BITS;
    const unsigned NB = 1u << BITS;
    int j = blockIdx.x * blockDim.x + threadIdx.x;
    if (j >= m) return;
    unsigned lo_k = (j == 0) ? 0u : ((((unsigned)table[j - 1]) >> SH) + 1u);
    unsigned hi_k = ((unsigned)table[j]) >> SH;
    for (unsigned k = lo_k; k <= hi_k; ++k) aux[k] = j;
    if (j == m - 1) {
        for (unsigned k = hi_k + 1; k <= NB; ++k) aux[k] = m;
    }
}

// ---- build 2: per-cell signature, sequential reads, plain store ----
template <int BITS>
__global__ __launch_bounds__(256) void build_sigs(
    const int* __restrict__ table, const int* __restrict__ aux, int z,
    u64* __restrict__ filter) {
    const int SH = 31 - BITS;
    const unsigned NB = 1u << BITS;
    unsigned k = blockIdx.x * blockDim.x + threadIdx.x;
    if (k >= NB) return;
    int p = aux[k];
    u64 sig = 0;
    while (p < z && ((((unsigned)table[p]) >> SH) == k)) {
        sig |= sig_mask((unsigned)table[p]);
        ++p;
    }
    filter[k] = sig;
}

// ---- exact resolution for filter-positive lanes (cached loads) ----
template <int BITS>
__device__ __forceinline__ int resolve_window(
    int v, const int* __restrict__ table, const int* __restrict__ mapping,
    const int* __restrict__ aux, int z, int zch) {
    const int SH = 31 - BITS;
    unsigned k = ((unsigned)v) >> SH;
    int lo = aux[k];
    int hi = aux[k + 1];
    int s = lo & ~3;
    int e = (hi + 3) & ~3;
    if (e > z) e = z;
    int cnt = 0;
    bool eq = false;
    for (int p = s; p < e; p += 4) {
        int4 t = *(const int4*)(table + p);
        cnt += (t.x < v) + (t.y < v) + (t.z < v) + (t.w < v);
        eq = eq | (t.x == v) | (t.y == v) | (t.z == v) | (t.w == v);
    }
    if (eq) return mapping[s + cnt];
    return zch;
}

// ---- main: 16 values/thread, phase-sharded filter, forced-MLP gathers ----
// PASS: which filter half (value bit 30) this launch serves.
// SPARSE=false: store full int4 results (zch placeholders for other shard).
// SPARSE=true : store only true hits (r != zch), scalar 4B stores.
template <int BITS, int PASS, bool SPARSE>
__global__ __launch_bounds__(256, 5) void mch_remap_pass_kernel(
    const vint4* __restrict__ values4,
    const int* __restrict__ table,
    const int* __restrict__ mapping,
    const int* __restrict__ zch_p,
    const int* __restrict__ aux,
    const u64* __restrict__ filter,
    int* __restrict__ out,
    int q4, int z) {                     // q4 = int4 units per segment
    const int SH = 31 - BITS;
    const unsigned PBASE = ((unsigned)PASS) << (BITS - 1);   // hot-shard base cell

    int zch = *zch_p;
    int i = blockIdx.x * blockDim.x + threadIdx.x;
    if (i >= q4) return;

    vint4 va = __builtin_nontemporal_load(values4 + i);
    vint4 vb = __builtin_nontemporal_load(values4 + i + q4);
    vint4 vc = __builtin_nontemporal_load(values4 + i + 2 * q4);
    vint4 vd = __builtin_nontemporal_load(values4 + i + 3 * q4);
    int v[16] = {va.x, va.y, va.z, va.w, vb.x, vb.y, vb.z, vb.w,
                 vc.x, vc.y, vc.z, vc.w, vd.x, vd.y, vd.z, vd.w};

    // 16 independent gathers; inactive (other-shard) lanes redirect to a
    // wave-uniform dummy cell in the hot shard (coalesces to one request).
    unsigned act = 0;
    u64 w[16];
#pragma unroll
    for (int e = 0; e < 16; ++e) {
        unsigned k = ((unsigned)v[e]) >> SH;
        bool a = ((k >> (BITS - 1)) == (unsigned)PASS);
        if (a) act |= (1u << e);
        unsigned ke = a ? k : PBASE;
        w[e] = filter[ke];
    }
    // Force all 16 gather results live -> real 16-deep MLP (r3: VGPR=36
    // proved the compiler otherwise batches these ~2-4 deep).
    __builtin_amdgcn_sched_barrier(0);

    unsigned pm = 0;
#pragma unroll
    for (int e = 0; e < 16; ++e) {
        u64 mask = sig_mask((unsigned)v[e]);
        if (((w[e] & mask) == mask) && ((act >> e) & 1u)) pm |= (1u << e);
    }

    int r[16];
#pragma unroll
    for (int e = 0; e < 16; ++e) r[e] = zch;

    // Wave iterates max-over-lanes popcount(pm) times; each lane resolves
    // its own positive slot concurrently.
    while (pm) {
        int e = __builtin_ctz(pm);
        pm &= pm - 1;
        // 16-way register select, static indices only (stays in VGPRs)
        int a0 = (e & 1) ? v[1]  : v[0];
        int a1 = (e & 1) ? v[3]  : v[2];
        int a2 = (e & 1) ? v[5]  : v[4];
        int a3 = (e & 1) ? v[7]  : v[6];
        int a4 = (e & 1) ? v[9]  : v[8];
        int a5 = (e & 1) ? v[11] : v[10];
        int a6 = (e & 1) ? v[13] : v[12];
        int a7 = (e & 1) ? v[15] : v[14];
        int b0 = (e & 2) ? a1 : a0;
        int b1 = (e & 2) ? a3 : a2;
        int b2 = (e & 2) ? a5 : a4;
        int b3 = (e & 2) ? a7 : a6;
        int c0 = (e & 4) ? b1 : b0;
        int c1 = (e & 4) ? b3 : b2;
        int ve = (e & 8) ? c1 : c0;

        int rr = resolve_window<BITS>(ve, table, mapping, aux, z, zch);

#pragma unroll
        for (int j = 0; j < 16; ++j) r[j] = (e == j) ? rr : r[j];
    }

    if (!SPARSE) {
        vint4* out4 = (vint4*)out;
        vint4 oa, ob, oc, od;
        oa.x = r[0];  oa.y = r[1];  oa.z = r[2];  oa.w = r[3];
        ob.x = r[4];  ob.y = r[5];  ob.z = r[6];  ob.w = r[7];
        oc.x = r[8];  oc.y = r[9];  oc.z = r[10]; oc.w = r[11];
        od.x = r[12]; od.y = r[13]; od.z = r[14]; od.w = r[15];
        __builtin_nontemporal_store(oa, out4 + i);
        __builtin_nontemporal_store(ob, out4 + i + q4);
        __builtin_nontemporal_store(oc, out4 + i + 2 * q4);
        __builtin_nontemporal_store(od, out4 + i + 3 * q4);
    } else {
        // Placeholders from pass 0 are already correct for every non-hit;
        // only true hits (~0.1% of slots) need a store.
#pragma unroll
        for (int e = 0; e < 16; ++e) {
            if (r[e] != zch) out[4 * (i + (e >> 2) * q4) + (e & 3)] = r[e];
        }
    }
}

// scalar tail (n % 16 != 0) — full filter, both shards, launched last
template <int BITS>
__global__ __launch_bounds__(64) void mch_remap_tail_kernel(
    const int* __restrict__ values, const int* __restrict__ table,
    const int* __restrict__ mapping, const int* __restrict__ zch_p,
    const int* __restrict__ aux, const u64* __restrict__ filter,
    int* __restrict__ out, int start, int n, int z) {
    const int SH = 31 - BITS;
    int i = start + blockIdx.x * blockDim.x + threadIdx.x;
    if (i >= n) return;
    int v = values[i];
    u64 w = filter[((unsigned)v) >> SH];
    u64 mask = sig_mask((unsigned)v);
    int zch = *zch_p;
    out[i] = ((w & mask) == mask)
                 ? resolve_window<BITS>(v, table, mapping, aux, z, zch) : zch;
}

// ---- fallback: aux-only windowed count, ~2 MB ws ----
__global__ __launch_bounds__(256) void mch_remap_aux_kernel(
    const int* __restrict__ values, const int* __restrict__ table,
    const int* __restrict__ mapping, const int* __restrict__ zch_p,
    const int* __restrict__ aux, int* __restrict__ out, int n, int z) {
    int zch = *zch_p;
    int i = blockIdx.x * blockDim.x + threadIdx.x;
    if (i >= n) return;
    int v = __builtin_nontemporal_load(values + i);
    out[i] = resolve_window<19>(v, table, mapping, aux, z, zch);
}

template <int BITS>
static void run_bloom(const int* values, const int* table, const int* mapping,
                      const int* zch_p, int* out, int n, int z, int m,
                      void* d_ws, hipStream_t stream) {
    const unsigned NB = 1u << BITS;
    u64* filter = (u64*)d_ws;
    int* aux = (int*)((char*)d_ws + (size_t)NB * 8);
    const int block = 256;

    build_aux_scatter<BITS><<<(m + block - 1) / block, block, 0, stream>>>(
        table, m, aux);
    build_sigs<BITS><<<((int)NB + block - 1) / block, block, 0, stream>>>(
        table, aux, z, filter);

    int q4 = n >> 4;                     // int4 units per segment (16 vals/thread)
    if (q4 > 0) {
        int grid = (q4 + block - 1) / block;
        mch_remap_pass_kernel<BITS, 0, false><<<grid, block, 0, stream>>>(
            (const vint4*)values, table, mapping, zch_p, aux, filter,
            out, q4, z);
        mch_remap_pass_kernel<BITS, 1, true><<<grid, block, 0, stream>>>(
            (const vint4*)values, table, mapping, zch_p, aux, filter,
            out, q4, z);
    }
    int done = (q4 << 4);
    if (done < n) {
        mch_remap_tail_kernel<BITS><<<((n - done) + 63) / 64, 64, 0, stream>>>(
            values, table, mapping, zch_p, aux, filter, out, done, n, z);
    }
}

extern "C" void kernel_launch(void* const* d_in, const int* in_sizes, int n_in,
                              void* d_out, int out_size, void* d_ws, size_t ws_size,
                              hipStream_t stream) {
    const int* values  = (const int*)d_in[0];
    const int* table   = (const int*)d_in[1];
    const int* mapping = (const int*)d_in[2];
    const int* zch_p   = (const int*)d_in[3];
    int* out = (int*)d_out;

    int n = in_sizes[0];          // 33_554_432
    int z = in_sizes[1];          // 4_194_304
    int m = z - 1;

    const size_t need19 = (size_t)(1u << 19) * 8 + ((size_t)(1u << 19) + 1) * 4;
    const size_t aux19  = ((size_t)(1u << 19) + 1) * 4;
    const int block = 256;

    if (ws_size >= need19) {
        run_bloom<19>(values, table, mapping, zch_p, out, n, z, m, d_ws, stream);
    } else if (ws_size >= aux19) {
        int* aux = (int*)d_ws;
        build_aux_scatter<19><<<(m + block - 1) / block, block, 0, stream>>>(
            table, m, aux);
        mch_remap_aux_kernel<<<(n + block - 1) / block, block, 0, stream>>>(
            values, table, mapping, zch_p, aux, out, n, z);
    }
}